// Round 8
// baseline (94.915 us; speedup 1.0000x reference)
//
#include <hip/hip_runtime.h>
#include <math.h>

constexpr int BN   = 8192;   // batch
constexpr int CN   = 4096;   // classes
constexpr int NT   = 512;    // threads per block (8 waves)
constexpr int NW   = NT / 64;
constexpr int EPT  = CN / NT;    // 8 elements per thread
constexpr int ROWS = 8;          // rows per block (software-pipelined)
constexpr int GRID = BN / ROWS;  // 1024 blocks -> 4 blocks/CU, 32 waves/CU

// Stage one 16KB x-row into LDS via global_load_lds (no VGPR round-trip).
// Linear layout: lane-order == address-order (wave-uniform base + lane*16).
__device__ __forceinline__ void stage_row(const float* __restrict__ gsrc,
                                          float* ldst, int tid) {
    #pragma unroll
    for (int i = 0; i < CN / (NT * 4); ++i) {       // 2 issues of 16B/lane
        const float* s = gsrc + (size_t)(tid + i * NT) * 4;
        float*       d = ldst + (size_t)(tid + i * NT) * 4;
        __builtin_amdgcn_global_load_lds(
            (const __attribute__((address_space(1))) void*)s,
            (__attribute__((address_space(3))) void*)d, 16, 0, 0);
    }
}

// Persistent block: 8 rows, double-buffered x staging, 3 barriers/row.
//   ws[b]      = sum_j log2_pijk  (sc partial, negative)
//   ws[BN + b] = -logp[b, target[b]]
__global__ __launch_bounds__(NT, 8) void sc_row_kernel(
    const float* __restrict__ x,
    const int*   __restrict__ target,
    const int*   __restrict__ distance_rank,
    const int*   __restrict__ k_idx,
    float*       __restrict__ ws)
{
    __shared__ float xs[2][CN];      // ping-pong row buffer; overwritten by Lp
    __shared__ float red_m[NW], red_s[NW], red_a[NW];

    const int tid  = threadIdx.x;
    const int lane = tid & 63;
    const int wave = tid >> 6;
    const int b0   = blockIdx.x * ROWS;

    // ---- prologue: row 0 staged + rank row prefetched
    int t_cur = target[b0];
    stage_row(x + (size_t)b0 * CN, xs[0], tid);
    const int* dr0 = distance_rank + (size_t)t_cur * CN;
    int rkv[EPT];
    #pragma unroll
    for (int i = 0; i < EPT; ++i) rkv[i] = dr0[tid + i * NT];
    int rk1 = dr0[1];
    __syncthreads();   // row 0 x in LDS

    for (int r = 0; r < ROWS; ++r) {
        const int cur = r & 1;
        const int b   = b0 + r;
        float* X = xs[cur];

        // ---- prefetch next row (x -> other buffer, rank row -> regs) and
        //      current row's k indices (used after B2)
        int rkvN[EPT], rk1N = 0, tN = 0;
        if (r + 1 < ROWS) {
            tN = target[b + 1];
            stage_row(x + (size_t)(b + 1) * CN, xs[cur ^ 1], tid);
            const int* drN = distance_rank + (size_t)tN * CN;
            #pragma unroll
            for (int i = 0; i < EPT; ++i) rkvN[i] = drN[tid + i * NT];
            rk1N = drN[1];
        }
        const int* krow = k_idx + (size_t)b * (CN - 3);
        int kkv[EPT];
        #pragma unroll
        for (int i = 0; i < EPT; ++i) {
            const int c  = tid + i * NT;
            const int jj = (c < 2) ? 0 : ((c > CN - 2) ? (CN - 4) : (c - 2));
            kkv[i] = krow[jj];
        }

        // ---- phase 1: softmax-local + ALL x-state reads of X
        float4 v0 = reinterpret_cast<float4*>(X)[tid];
        float4 v1 = reinterpret_cast<float4*>(X)[tid + NT];
        float ml = fmaxf(fmaxf(fmaxf(v0.x, v0.y), fmaxf(v0.z, v0.w)),
                         fmaxf(fmaxf(v1.x, v1.y), fmaxf(v1.z, v1.w)));
        float sl = __expf(v0.x-ml)+__expf(v0.y-ml)+__expf(v0.z-ml)+__expf(v0.w-ml)
                 + __expf(v1.x-ml)+__expf(v1.y-ml)+__expf(v1.z-ml)+__expf(v1.w-ml);
        #pragma unroll
        for (int off = 32; off; off >>= 1) {
            const float mo = __shfl_down(ml, off, 64);
            const float so = __shfl_down(sl, off, 64);
            const float mn = fmaxf(ml, mo);
            sl = sl * __expf(ml - mn) + so * __expf(mo - mn);
            ml = mn;
        }
        if (lane == 0) { red_m[wave] = ml; red_s[wave] = sl; }

        const float xt = X[t_cur];        // broadcast read
        const float yi = X[rk1];          // broadcast read
        float yv[EPT];
        #pragma unroll
        for (int i = 0; i < EPT; ++i) yv[i] = X[rkv[i]];   // random gather

        __syncthreads();   // B1: red ready; all x-state reads complete

        // ---- phase 2: softmax merge + CE; overwrite X with Lp
        float mg = red_m[0];
        #pragma unroll
        for (int w = 1; w < NW; ++w) mg = fmaxf(mg, red_m[w]);
        float sg = 0.f;
        #pragma unroll
        for (int w = 0; w < NW; ++w) sg += red_s[w] * __expf(red_m[w] - mg);
        if (tid == 0) ws[BN + b] = __logf(sg) + mg - xt;

        const float alpha = (float)(CN - 1);
        float Lq[EPT];
        #pragma unroll
        for (int i = 0; i < EPT; ++i) {
            const int   c = tid + i * NT;
            const float d = yi - yv[i];
            Lq[i] = __log2f(fmaf(d, d, alpha));
            X[c]  = Lq[i];                 // conflict-free stride-1 store
        }
        __syncthreads();   // B2: Lp ready

        // ---- phase 3: j-loop, j = c-2 so Lj == Lq[i] (register-resident)
        const float e = -0.5f * (float)CN;
        float acc = 0.f;
        #pragma unroll
        for (int i = 0; i < EPT; ++i) {
            const int   c  = tid + i * NT;
            const float Lk = X[kkv[i]];    // single random gather
            const float D  = e * (Lk - Lq[i]);
            const float term = fmaxf(D, 0.f)
                + __log2f(1.0f + __builtin_amdgcn_exp2f(-fabsf(D)));
            acc -= (c >= 2 && c <= CN - 2) ? term : 0.f;
        }
        #pragma unroll
        for (int off = 32; off; off >>= 1) acc += __shfl_down(acc, off, 64);
        if (lane == 0) red_a[wave] = acc;
        __syncthreads();   // B3: red_a ready; X reads done (safe to restage)
        if (tid == 0) {
            float a0 = red_a[0];
            #pragma unroll
            for (int w = 1; w < NW; ++w) a0 += red_a[w];
            ws[b] = a0;
        }

        // rotate prefetched state
        t_cur = tN; rk1 = rk1N;
        #pragma unroll
        for (int i = 0; i < EPT; ++i) rkv[i] = rkvN[i];
    }
}

// Deterministic final reduction of the 2*BN partials, double accumulation.
__global__ __launch_bounds__(1024) void sc_finalize(
    const float* __restrict__ ws, float* __restrict__ out)
{
    __shared__ double dred[32];
    const int tid  = threadIdx.x;
    const int lane = tid & 63;
    const int wave = tid >> 6;

    double sc = 0.0, ce = 0.0;
    for (int i = tid; i < BN; i += 1024) {
        sc += (double)ws[i];
        ce += (double)ws[BN + i];
    }
    for (int off = 32; off; off >>= 1) {
        sc += __shfl_down(sc, off, 64);
        ce += __shfl_down(ce, off, 64);
    }
    if (lane == 0) { dred[wave] = sc; dred[16 + wave] = ce; }
    __syncthreads();
    if (tid == 0) {
        double scs = 0.0, ces = 0.0;
        #pragma unroll
        for (int w = 0; w < 16; ++w) { scs += dred[w]; ces += dred[16 + w]; }
        double ce_mean = ces / (double)BN;
        double sc_val  = -scs / (double)BN / (double)(CN - 1);
        out[0] = (float)(0.6 * ce_mean + 0.4 * sc_val);
    }
}

extern "C" void kernel_launch(void* const* d_in, const int* in_sizes, int n_in,
                              void* d_out, int out_size, void* d_ws, size_t ws_size,
                              hipStream_t stream) {
    const float* x             = (const float*)d_in[0];
    const int*   target        = (const int*)d_in[1];
    const int*   distance_rank = (const int*)d_in[2];
    const int*   k_idx         = (const int*)d_in[3];
    float*       ws            = (float*)d_ws;

    sc_row_kernel<<<GRID, NT, 0, stream>>>(x, target, distance_rank, k_idx, ws);
    sc_finalize<<<1, 1024, 0, stream>>>(ws, (float*)d_out);
}

// Round 9
// 68.353 us; speedup vs baseline: 1.3886x; 1.3886x over previous
//
#include <hip/hip_runtime.h>
#include <math.h>

constexpr int BN  = 8192;   // batch
constexpr int CN  = 4096;   // classes
constexpr int NT  = 256;    // threads per block (4 waves) -> 8 blocks/CU
constexpr int NW  = NT / 64;
constexpr int EPT = CN / NT;   // 16 scalar elements per thread
constexpr int V4  = EPT / 4;   // 4 float4 per thread

// One block per batch row. xs is overwritten in place by Lp after the gather
// phase (16.9 KB LDS -> 8 blocks/CU). All global loads issued at entry into
// registers so HBM latency hides under softmax+gather phases.
//   ws[b]      = sum_j log2_pijk  (sc partial, negative)
//   ws[BN + b] = -logp[b, target[b]]  (ce per-row term)
__global__ __launch_bounds__(NT) void sc_row_kernel(
    const float* __restrict__ x,
    const int*   __restrict__ target,
    const int*   __restrict__ distance_rank,
    const int*   __restrict__ k_idx,
    float*       __restrict__ ws)
{
    __shared__ float xs[CN];          // phase 1-2: x row; phase 3+: Lp values
    __shared__ float red_m[NW], red_s[NW], red_a[NW];

    const int b    = blockIdx.x;
    const int tid  = threadIdx.x;
    const int lane = tid & 63;
    const int wave = tid >> 6;

    const int t = target[b];
    const float* __restrict__ xrow = x + (size_t)b * CN;
    const int*   __restrict__ drow = distance_rank + (size_t)t * CN;
    const int*   __restrict__ krow = k_idx + (size_t)b * (CN - 3);

    // ---- entry: ALL global loads issued here.
    // k indices (HBM stream, consumed 3 barriers later in the j-loop):
    int kkv[EPT];
    #pragma unroll
    for (int i = 0; i < EPT; ++i) {
        const int c = tid + i * NT;
        const int j = (c < 2) ? 0 : ((c > CN - 2) ? (CN - 4) : (c - 2));
        kkv[i] = krow[j];
    }
    // rank entries (L3-resident matrix), consumed in the gather phase:
    int rkv[EPT];
    #pragma unroll
    for (int i = 0; i < EPT; ++i) rkv[i] = drow[tid + i * NT];
    const int rk1 = drow[1];          // broadcast (same addr all threads)

    // x row staged to LDS via registers (registers reused for online softmax):
    float4 xv[V4];
    #pragma unroll
    for (int i = 0; i < V4; ++i) {
        xv[i] = reinterpret_cast<const float4*>(xrow)[tid + i * NT];
        reinterpret_cast<float4*>(xs)[tid + i * NT] = xv[i];
    }

    // ---- online softmax on register copies
    float ml = -__builtin_huge_valf();
    #pragma unroll
    for (int i = 0; i < V4; ++i) {
        ml = fmaxf(ml, fmaxf(fmaxf(xv[i].x, xv[i].y), fmaxf(xv[i].z, xv[i].w)));
    }
    float sl = 0.f;
    #pragma unroll
    for (int i = 0; i < V4; ++i) {
        sl += __expf(xv[i].x - ml) + __expf(xv[i].y - ml)
            + __expf(xv[i].z - ml) + __expf(xv[i].w - ml);
    }
    #pragma unroll
    for (int off = 32; off; off >>= 1) {
        const float mo = __shfl_down(ml, off, 64);
        const float so = __shfl_down(sl, off, 64);
        const float mn = fmaxf(ml, mo);
        sl = sl * __expf(ml - mn) + so * __expf(mo - mn);
        ml = mn;
    }
    if (lane == 0) { red_m[wave] = ml; red_s[wave] = sl; }

    __syncthreads();   // B1: xs staged, per-wave (m,s) visible

    float mg = red_m[0];
    #pragma unroll
    for (int w = 1; w < NW; ++w) mg = fmaxf(mg, red_m[w]);
    float sg = 0.f;
    #pragma unroll
    for (int w = 0; w < NW; ++w) sg += red_s[w] * __expf(red_m[w] - mg);

    if (tid == 0) ws[BN + b] = __logf(sg) + mg - xs[t];   // -logp[target]

    // ---- gather phase: all xs reads complete before overwrite
    const float yi = xs[rk1];
    float yv[EPT];
    #pragma unroll
    for (int i = 0; i < EPT; ++i) yv[i] = xs[rkv[i]];     // random LDS gather

    __syncthreads();   // B2: every thread done reading xs

    // ---- in-place transform: xs[c] <- Lp[c] = log2(alpha + (yi - y_c)^2)
    //      Lq kept in registers: thread handling position c owns Lj for j=c-2.
    const float alpha = (float)(CN - 1);
    float Lq[EPT];
    #pragma unroll
    for (int i = 0; i < EPT; ++i) {
        const int   c = tid + i * NT;
        const float d = yi - yv[i];
        Lq[i] = __log2f(fmaf(d, d, alpha));
        xs[c] = Lq[i];                                    // conflict-free store
    }
    __syncthreads();   // B3: Lp ready

    // ---- sc term (j = c-2):  D = e*(Lp[kk] - Lq);
    //      log2_pijk = -(max(D,0) + log2(1 + 2^-|D|))
    const float e = -0.5f * (float)CN;
    float acc = 0.f;
    #pragma unroll
    for (int i = 0; i < EPT; ++i) {
        const int   c  = tid + i * NT;
        const float Lk = xs[kkv[i]];                      // single random gather
        const float D  = e * (Lk - Lq[i]);
        const float term = fmaxf(D, 0.f)
                         + __log2f(1.0f + __builtin_amdgcn_exp2f(-fabsf(D)));
        acc -= (c >= 2 && c <= CN - 2) ? term : 0.f;
    }

    #pragma unroll
    for (int off = 32; off; off >>= 1) acc += __shfl_down(acc, off, 64);
    if (lane == 0) red_a[wave] = acc;
    __syncthreads();
    if (tid == 0) {
        float a0 = red_a[0];
        #pragma unroll
        for (int w = 1; w < NW; ++w) a0 += red_a[w];
        ws[b] = a0;
    }
}

// Deterministic final reduction of the 2*BN partials, double accumulation.
__global__ __launch_bounds__(1024) void sc_finalize(
    const float* __restrict__ ws, float* __restrict__ out)
{
    __shared__ double dred[32];
    const int tid  = threadIdx.x;
    const int lane = tid & 63;
    const int wave = tid >> 6;

    double sc = 0.0, ce = 0.0;
    for (int i = tid; i < BN; i += 1024) {
        sc += (double)ws[i];
        ce += (double)ws[BN + i];
    }
    for (int off = 32; off; off >>= 1) {
        sc += __shfl_down(sc, off, 64);
        ce += __shfl_down(ce, off, 64);
    }
    if (lane == 0) { dred[wave] = sc; dred[16 + wave] = ce; }
    __syncthreads();
    if (tid == 0) {
        double scs = 0.0, ces = 0.0;
        #pragma unroll
        for (int w = 0; w < 16; ++w) { scs += dred[w]; ces += dred[16 + w]; }
        double ce_mean = ces / (double)BN;
        double sc_val  = -scs / (double)BN / (double)(CN - 1);
        out[0] = (float)(0.6 * ce_mean + 0.4 * sc_val);
    }
}

extern "C" void kernel_launch(void* const* d_in, const int* in_sizes, int n_in,
                              void* d_out, int out_size, void* d_ws, size_t ws_size,
                              hipStream_t stream) {
    const float* x             = (const float*)d_in[0];
    const int*   target        = (const int*)d_in[1];
    const int*   distance_rank = (const int*)d_in[2];
    const int*   k_idx         = (const int*)d_in[3];
    float*       ws            = (float*)d_ws;

    sc_row_kernel<<<BN, NT, 0, stream>>>(x, target, distance_rank, k_idx, ws);
    sc_finalize<<<1, 1024, 0, stream>>>(ws, (float*)d_out);
}